// Round 3
// baseline (541.396 us; speedup 1.0000x reference)
//
#include <hip/hip_runtime.h>
#include <hip/hip_bf16.h>
#include <math.h>

#define Nn 20480
#define Cc 128
#define Hh 8
#define Ll 4
#define NWw 320
#define BN 81920   // B*N

typedef short sv8 __attribute__((ext_vector_type(8)));
typedef __bf16 bfv8 __attribute__((ext_vector_type(8)));
typedef float f32x4 __attribute__((ext_vector_type(4)));

__device__ __forceinline__ f32x4 mfma16(sv8 a, sv8 b, f32x4 c) {
    return __builtin_amdgcn_mfma_f32_16x16x32_bf16(
        __builtin_bit_cast(bfv8, a), __builtin_bit_cast(bfv8, b), c, 0, 0, 0);
}
__device__ __forceinline__ ushort f2bf(float f) {
    uint u = __float_as_uint(f);
    u += 0x7fffu + ((u >> 16) & 1u);
    return (ushort)(u >> 16);
}
__device__ __forceinline__ float fast_gelu(float x) {
    float z = 0.7978845608f * (x + 0.044715f * x * x * x);
    return x * __builtin_amdgcn_rcpf(1.0f + __expf(-2.0f * z));
}

// ---------- stable counting sort of window_ids ----------
__global__ __launch_bounds__(64) void rank_kernel(const int* __restrict__ wid,
        int* __restrict__ lrank, int* __restrict__ hist) {
    __shared__ int keys[64];
    int c = blockIdx.x, lane = threadIdx.x;
    for (int j = lane; j < NWw; j += 64) hist[c * NWw + j] = 0;
    int i = c * 64 + lane;
    int w = wid[i];
    keys[lane] = w;
    __syncthreads();
    int rank = 0, total = 0;
    for (int j = 0; j < 64; ++j) {
        int kj = keys[j];
        total += (kj == w);
        rank += (j < lane && kj == w) ? 1 : 0;
    }
    lrank[i] = rank;
    if (rank == 0) hist[c * NWw + w] = total;
}
__global__ __launch_bounds__(64) void prefix_kernel(int* __restrict__ hist) {
    int w = blockIdx.x, lane = threadIdx.x;
    int running = 0;
    for (int it = 0; it < NWw / 64; ++it) {
        int c = it * 64 + lane;
        int v = hist[c * NWw + w];
        int orig = v;
        #pragma unroll
        for (int d = 1; d < 64; d <<= 1) {
            int tt = __shfl_up(v, d, 64);
            if (lane >= d) v += tt;
        }
        hist[c * NWw + w] = running + v - orig;
        running += __shfl(v, 63, 64);
    }
}
__global__ __launch_bounds__(64) void scatter_kernel(const int* __restrict__ wid,
        const int* __restrict__ lrank, const int* __restrict__ hist,
        int* __restrict__ sidx) {
    int c = blockIdx.x, lane = threadIdx.x;
    int i = c * 64 + lane;
    int w = wid[i];
    sidx[w * 64 + hist[c * NWw + w] + lrank[i]] = i;
}

// ---------- weight convert + transpose to bf16 [N][K] ----------
__global__ __launch_bounds__(256) void wconv_kernel(
    const float* __restrict__ Wqkv, const float* __restrict__ Wproj,
    const float* __restrict__ W1, const float* __restrict__ W2,
    ushort* __restrict__ wt) {
    int id = blockIdx.x * 256 + threadIdx.x;      // < 786432
    int l = id / 196608;
    int r = id % 196608;
    const float* src; int dst;
    if (r < 49152) { int n = r % 384, k = r / 384;
        src = Wqkv + l * 49152 + k * 384 + n; dst = l * 196608 + n * 128 + k; }
    else if (r < 65536) { int rr = r - 49152; int n = rr % 128, k = rr / 128;
        src = Wproj + l * 16384 + k * 128 + n; dst = l * 196608 + 49152 + n * 128 + k; }
    else if (r < 131072) { int rr = r - 65536; int n = rr % 512, k = rr / 512;
        src = W1 + l * 65536 + k * 512 + n; dst = l * 196608 + 65536 + n * 128 + k; }
    else { int rr = r - 131072; int n = rr % 128, k = rr / 128;
        src = W2 + l * 65536 + k * 128 + n; dst = l * 196608 + 131072 + n * 512 + k; }
    wt[dst] = f2bf(*src);
}

// ---------- fused attention block ----------
// one block per (batch, window): 256 threads / 4 waves, 64 tokens
__global__ __launch_bounds__(256, 2) void attn_fused_kernel(
    const float* __restrict__ xsrc, float* __restrict__ xdst,
    const ushort* __restrict__ wqkvT, const float* __restrict__ bqkv,
    const float* __restrict__ relb, const ushort* __restrict__ wprojT,
    const float* __restrict__ bproj, const float* __restrict__ g1,
    const float* __restrict__ be1, const int* __restrict__ sidx) {
    __shared__ __align__(16) ushort hl_[64][128];   // LN out; reused as attn-out
    __shared__ __align__(16) ushort qkn[64][256];   // q|k (swizzled)
    __shared__ __align__(16) ushort vT[128][76];    // V transposed [d][k]
    __shared__ __align__(16) ushort pt[4][16][76];  // P stage per wave
    __shared__ int ridx[64];

    int t = threadIdx.x;
    int wave = t >> 6, lane = t & 63;
    int lr = lane & 15, lg = lane >> 4;
    int wb = blockIdx.x;
    int bN = (wb / NWw) * Nn;
    int p0 = (wb % NWw) * 64;

    if (t < 64) ridx[t] = sidx[p0 + t];
    __syncthreads();

    // ---- phase 1: gather + LN1 -> hl_ (bf16, swizzled)
    {
        int hl2 = lane & 31, hb = lane >> 5;
        float4 gg = *(const float4*)(g1 + hl2 * 4);
        float4 bb = *(const float4*)(be1 + hl2 * 4);
        #pragma unroll
        for (int it = 0; it < 8; ++it) {
            int row = it * 8 + wave * 2 + hb;
            int gi = bN + ridx[row];
            float4 v = *(const float4*)(xsrc + (size_t)gi * Cc + hl2 * 4);
            float s = v.x + v.y + v.z + v.w;
            s += __shfl_xor(s, 1, 64);  s += __shfl_xor(s, 2, 64);
            s += __shfl_xor(s, 4, 64);  s += __shfl_xor(s, 8, 64);
            s += __shfl_xor(s, 16, 64);
            float mu = s * 0.0078125f;
            float d0 = v.x - mu, d1 = v.y - mu, d2 = v.z - mu, d3 = v.w - mu;
            float q = d0 * d0 + d1 * d1 + d2 * d2 + d3 * d3;
            q += __shfl_xor(q, 1, 64);  q += __shfl_xor(q, 2, 64);
            q += __shfl_xor(q, 4, 64);  q += __shfl_xor(q, 8, 64);
            q += __shfl_xor(q, 16, 64);
            float rs = rsqrtf(q * 0.0078125f + 1e-5f);
            uint2 pk;
            pk.x = (uint)f2bf(d0 * rs * gg.x + bb.x) | ((uint)f2bf(d1 * rs * gg.y + bb.y) << 16);
            pk.y = (uint)f2bf(d2 * rs * gg.z + bb.z) | ((uint)f2bf(d3 * rs * gg.w + bb.w) << 16);
            *(uint2*)&hl_[row][(hl2 * 4) ^ ((row & 7) << 3)] = pk;
        }
    }
    __syncthreads();

    // ---- phase 2: QKV GEMM; wave computes its own 2 heads' q,k,v (96 cols)
    {
        f32x4 acc[4][6] = {};
        #pragma unroll
        for (int ks = 0; ks < 4; ++ks) {
            int k0 = ks * 32 + lg * 8;
            sv8 a[4], b[6];
            #pragma unroll
            for (int rf = 0; rf < 4; ++rf) {
                int row = rf * 16 + lr;
                a[rf] = *(const sv8*)&hl_[row][k0 ^ ((row & 7) << 3)];
            }
            #pragma unroll
            for (int nf = 0; nf < 6; ++nf) {
                int gcol = (nf < 2 ? 32 * wave + nf * 16
                          : nf < 4 ? 128 + 32 * wave + (nf - 2) * 16
                                   : 256 + 32 * wave + (nf - 4) * 16) + lr;
                b[nf] = *(const sv8*)(wqkvT + (size_t)gcol * 128 + k0);
            }
            #pragma unroll
            for (int rf = 0; rf < 4; ++rf)
                #pragma unroll
                for (int nf = 0; nf < 6; ++nf)
                    acc[rf][nf] = mfma16(a[rf], b[nf], acc[rf][nf]);
        }
        #pragma unroll
        for (int nf = 0; nf < 6; ++nf) {
            int gcol = (nf < 2 ? 32 * wave + nf * 16
                      : nf < 4 ? 128 + 32 * wave + (nf - 2) * 16
                               : 256 + 32 * wave + (nf - 4) * 16) + lr;
            float bs = bqkv[gcol];
            if (nf < 4) {
                #pragma unroll
                for (int rf = 0; rf < 4; ++rf)
                    #pragma unroll
                    for (int r = 0; r < 4; ++r) {
                        int row = rf * 16 + lg * 4 + r;
                        qkn[row][gcol ^ ((row & 7) << 3)] = f2bf(acc[rf][nf][r] + bs);
                    }
            } else {
                int dcol = gcol - 256;
                #pragma unroll
                for (int rf = 0; rf < 4; ++rf) {
                    uint2 pk;
                    pk.x = (uint)f2bf(acc[rf][nf][0] + bs) | ((uint)f2bf(acc[rf][nf][1] + bs) << 16);
                    pk.y = (uint)f2bf(acc[rf][nf][2] + bs) | ((uint)f2bf(acc[rf][nf][3] + bs) << 16);
                    *(uint2*)&vT[dcol][rf * 16 + lg * 4] = pk;
                }
            }
        }
    }
    __syncthreads();   // qkn/vT ready; hl_ reads done -> safe to overwrite as attn-out

    // ---- phase 3: attention via swapped QK^T (S^T = K Q^T), 2 heads per wave
    f32x4 zz = {0.f, 0.f, 0.f, 0.f};
    #pragma unroll
    for (int hi = 0; hi < 2; ++hi) {
        int hh = wave * 2 + hi;
        float rb = relb[hh];
        // V fragments: b128 from vT
        sv8 bv[2];
        #pragma unroll
        for (int ks = 0; ks < 2; ++ks)
            bv[ks] = *(const sv8*)&vT[hh * 16 + lr][ks * 32 + lg * 8];
        // Q/K fragments (K-dim padded 16->32, lg>=2 zero)
        sv8 aq[4], bk[4];
        sv8 z = {0, 0, 0, 0, 0, 0, 0, 0};
        bool lo = (lg < 2);
        #pragma unroll
        for (int f = 0; f < 4; ++f) {
            aq[f] = z; bk[f] = z;
            if (lo) {
                int row = f * 16 + lr;
                aq[f] = *(const sv8*)&qkn[row][(hh * 16 + lg * 8) ^ ((row & 7) << 3)];
                bk[f] = *(const sv8*)&qkn[row][(128 + hh * 16 + lg * 8) ^ ((row & 7) << 3)];
            }
        }
        // S^T: s[kt][qt] at lane(lr,lg) = S[q=qt*16+lr][k=kt*16+lg*4+r]
        f32x4 s[4][4];
        #pragma unroll
        for (int kt = 0; kt < 4; ++kt)
            #pragma unroll
            for (int qt = 0; qt < 4; ++qt)
                s[kt][qt] = mfma16(bk[kt], aq[qt], zz);

        f32x4 o[4];
        #pragma unroll
        for (int qt = 0; qt < 4; ++qt) {
            float v[16];
            #pragma unroll
            for (int kt = 0; kt < 4; ++kt)
                #pragma unroll
                for (int r = 0; r < 4; ++r)
                    v[kt * 4 + r] = s[kt][qt][r] * 0.25f + rb;
            // in-lane max tree (16) then 2 shuffles across lg
            float m0 = fmaxf(fmaxf(fmaxf(v[0], v[1]), fmaxf(v[2], v[3])),
                             fmaxf(fmaxf(v[4], v[5]), fmaxf(v[6], v[7])));
            float m1 = fmaxf(fmaxf(fmaxf(v[8], v[9]), fmaxf(v[10], v[11])),
                             fmaxf(fmaxf(v[12], v[13]), fmaxf(v[14], v[15])));
            float mx = fmaxf(m0, m1);
            mx = fmaxf(mx, __shfl_xor(mx, 16, 64));
            mx = fmaxf(mx, __shfl_xor(mx, 32, 64));
            float sum = 0.f;
            #pragma unroll
            for (int i = 0; i < 16; ++i) {
                v[i] = __expf(v[i] - mx);
                sum += v[i];
            }
            sum += __shfl_xor(sum, 16, 64);
            sum += __shfl_xor(sum, 32, 64);
            float inv = __builtin_amdgcn_rcpf(sum);
            // pack P -> pt[wave][q=lr][k], 4 consecutive k per write
            #pragma unroll
            for (int kt = 0; kt < 4; ++kt) {
                uint2 pk;
                pk.x = (uint)f2bf(v[kt * 4 + 0] * inv) | ((uint)f2bf(v[kt * 4 + 1] * inv) << 16);
                pk.y = (uint)f2bf(v[kt * 4 + 2] * inv) | ((uint)f2bf(v[kt * 4 + 3] * inv) << 16);
                *(uint2*)&pt[wave][lr][kt * 16 + lg * 4] = pk;
            }
            sv8 ap0 = *(const sv8*)&pt[wave][lr][lg * 8];
            sv8 ap1 = *(const sv8*)&pt[wave][lr][32 + lg * 8];
            o[qt] = mfma16(ap0, bv[0], zz);
            o[qt] = mfma16(ap1, bv[1], o[qt]);
        }
        #pragma unroll
        for (int qt = 0; qt < 4; ++qt)
            #pragma unroll
            for (int r = 0; r < 4; ++r) {
                int row = qt * 16 + lg * 4 + r;
                hl_[row][(hh * 16 + lr) ^ ((row & 7) << 3)] = f2bf(o[qt][r]);
            }
    }
    __syncthreads();

    // ---- phase 4: proj + bias + residual, scatter to original rows
    {
        f32x4 acc[4][2] = {};
        #pragma unroll
        for (int ks = 0; ks < 4; ++ks) {
            int k0 = ks * 32 + lg * 8;
            sv8 a[4], b[2];
            #pragma unroll
            for (int rf = 0; rf < 4; ++rf) {
                int row = rf * 16 + lr;
                a[rf] = *(const sv8*)&hl_[row][k0 ^ ((row & 7) << 3)];
            }
            #pragma unroll
            for (int nf = 0; nf < 2; ++nf)
                b[nf] = *(const sv8*)(wprojT + (size_t)(wave * 32 + nf * 16 + lr) * 128 + k0);
            #pragma unroll
            for (int rf = 0; rf < 4; ++rf)
                #pragma unroll
                for (int nf = 0; nf < 2; ++nf)
                    acc[rf][nf] = mfma16(a[rf], b[nf], acc[rf][nf]);
        }
        #pragma unroll
        for (int nf = 0; nf < 2; ++nf) {
            int col = wave * 32 + nf * 16 + lr;
            float bs = bproj[col];
            #pragma unroll
            for (int rf = 0; rf < 4; ++rf)
                #pragma unroll
                for (int r = 0; r < 4; ++r) {
                    int row = rf * 16 + lg * 4 + r;
                    int gi = bN + ridx[row];
                    size_t ad = (size_t)gi * Cc + col;
                    xdst[ad] = xsrc[ad] + acc[rf][nf][r] + bs;
                }
        }
    }
}

// ---------- fused MLP block: LN2 -> MLP1+GELU -> MLP2+residual (split-K hidden) ----------
__global__ __launch_bounds__(256, 3) void mlp_fused_kernel(
    const float* __restrict__ xsrc, float* __restrict__ xdst,
    const ushort* __restrict__ w1T, const float* __restrict__ b1,
    const ushort* __restrict__ w2T, const float* __restrict__ b2,
    const float* __restrict__ g2, const float* __restrict__ be2) {
    __shared__ __align__(16) ushort hl_[64][128];
    __shared__ __align__(16) ushort hid[64][256];
    int t = threadIdx.x, wave = t >> 6, lane = t & 63;
    int lr = lane & 15, lg = lane >> 4;
    int r0 = blockIdx.x * 64;

    // phase 1: LN2
    {
        int hl2 = lane & 31, hb = lane >> 5;
        float4 gg = *(const float4*)(g2 + hl2 * 4);
        float4 bb = *(const float4*)(be2 + hl2 * 4);
        #pragma unroll
        for (int it = 0; it < 8; ++it) {
            int row = it * 8 + wave * 2 + hb;
            float4 v = *(const float4*)(xsrc + (size_t)(r0 + row) * Cc + hl2 * 4);
            float s = v.x + v.y + v.z + v.w;
            s += __shfl_xor(s, 1, 64);  s += __shfl_xor(s, 2, 64);
            s += __shfl_xor(s, 4, 64);  s += __shfl_xor(s, 8, 64);
            s += __shfl_xor(s, 16, 64);
            float mu = s * 0.0078125f;
            float d0 = v.x - mu, d1 = v.y - mu, d2 = v.z - mu, d3 = v.w - mu;
            float q = d0 * d0 + d1 * d1 + d2 * d2 + d3 * d3;
            q += __shfl_xor(q, 1, 64);  q += __shfl_xor(q, 2, 64);
            q += __shfl_xor(q, 4, 64);  q += __shfl_xor(q, 8, 64);
            q += __shfl_xor(q, 16, 64);
            float rs = rsqrtf(q * 0.0078125f + 1e-5f);
            uint2 pk;
            pk.x = (uint)f2bf(d0 * rs * gg.x + bb.x) | ((uint)f2bf(d1 * rs * gg.y + bb.y) << 16);
            pk.y = (uint)f2bf(d2 * rs * gg.z + bb.z) | ((uint)f2bf(d3 * rs * gg.w + bb.w) << 16);
            *(uint2*)&hl_[row][(hl2 * 4) ^ ((row & 7) << 3)] = pk;
        }
    }
    __syncthreads();

    f32x4 acc2[4][2] = {};
    #pragma unroll
    for (int hf = 0; hf < 2; ++hf) {
        // MLP1 half: wave computes hid local cols [wave*64, wave*64+64)
        f32x4 acc[4][4] = {};
        #pragma unroll
        for (int ks = 0; ks < 4; ++ks) {
            int k0 = ks * 32 + lg * 8;
            sv8 a[4], b[4];
            #pragma unroll
            for (int rf = 0; rf < 4; ++rf) {
                int row = rf * 16 + lr;
                a[rf] = *(const sv8*)&hl_[row][k0 ^ ((row & 7) << 3)];
            }
            #pragma unroll
            for (int nf = 0; nf < 4; ++nf)
                b[nf] = *(const sv8*)(w1T + (size_t)(hf * 256 + wave * 64 + nf * 16 + lr) * 128 + k0);
            #pragma unroll
            for (int rf = 0; rf < 4; ++rf)
                #pragma unroll
                for (int nf = 0; nf < 4; ++nf)
                    acc[rf][nf] = mfma16(a[rf], b[nf], acc[rf][nf]);
        }
        #pragma unroll
        for (int nf = 0; nf < 4; ++nf) {
            int lcol = wave * 64 + nf * 16 + lr;
            float bs = b1[hf * 256 + lcol];
            #pragma unroll
            for (int rf = 0; rf < 4; ++rf)
                #pragma unroll
                for (int r = 0; r < 4; ++r) {
                    int row = rf * 16 + lg * 4 + r;
                    hid[row][lcol ^ ((row & 7) << 3)] = f2bf(fast_gelu(acc[rf][nf][r] + bs));
                }
        }
        __syncthreads();
        // MLP2 partial over this K half
        #pragma unroll
        for (int ks = 0; ks < 8; ++ks) {
            int k0 = ks * 32 + lg * 8;
            sv8 a[4], b[2];
            #pragma unroll
            for (int rf = 0; rf < 4; ++rf) {
                int row = rf * 16 + lr;
                a[rf] = *(const sv8*)&hid[row][k0 ^ ((row & 7) << 3)];
            }
            #pragma unroll
            for (int nf = 0; nf < 2; ++nf)
                b[nf] = *(const sv8*)(w2T + (size_t)(wave * 32 + nf * 16 + lr) * 512 + hf * 256 + k0);
            #pragma unroll
            for (int rf = 0; rf < 4; ++rf)
                #pragma unroll
                for (int nf = 0; nf < 2; ++nf)
                    acc2[rf][nf] = mfma16(a[rf], b[nf], acc2[rf][nf]);
        }
        if (hf == 0) __syncthreads();   // protect hid before overwrite
    }

    // epilogue: bias + residual
    #pragma unroll
    for (int nf = 0; nf < 2; ++nf) {
        int col = wave * 32 + nf * 16 + lr;
        float bs = b2[col];
        #pragma unroll
        for (int rf = 0; rf < 4; ++rf)
            #pragma unroll
            for (int r = 0; r < 4; ++r) {
                int row = rf * 16 + lg * 4 + r;
                size_t ad = (size_t)(r0 + row) * Cc + col;
                xdst[ad] = xsrc[ad] + acc2[rf][nf][r] + bs;
            }
    }
}

extern "C" void kernel_launch(void* const* d_in, const int* in_sizes, int n_in,
                              void* d_out, int out_size, void* d_ws, size_t ws_size,
                              hipStream_t stream) {
    const float* x_in   = (const float*)d_in[0];
    const float* g1     = (const float*)d_in[1];
    const float* be1    = (const float*)d_in[2];
    const float* Wqkv   = (const float*)d_in[3];
    const float* bqkv   = (const float*)d_in[4];
    const float* relb   = (const float*)d_in[5];
    const float* Wproj  = (const float*)d_in[6];
    const float* bproj  = (const float*)d_in[7];
    const float* g2     = (const float*)d_in[8];
    const float* be2    = (const float*)d_in[9];
    const float* W1     = (const float*)d_in[10];
    const float* b1     = (const float*)d_in[11];
    const float* W2     = (const float*)d_in[12];
    const float* b2     = (const float*)d_in[13];
    const int*   wid    = (const int*)d_in[14];

    size_t off = 0;
    float* x_ws = (float*)d_ws;                      off += (size_t)BN * Cc * 4;
    ushort* wt  = (ushort*)((char*)d_ws + off);      off += (size_t)786432 * 2;
    int* sidx   = (int*)((char*)d_ws + off);         off += (size_t)Nn * 4;
    int* lrank  = (int*)((char*)d_ws + off);         off += (size_t)Nn * 4;
    int* hist   = (int*)((char*)d_ws + off);         off += (size_t)NWw * NWw * 4;
    if (ws_size < off) return;

    rank_kernel<<<Nn / 64, 64, 0, stream>>>(wid, lrank, hist);
    prefix_kernel<<<NWw, 64, 0, stream>>>(hist);
    scatter_kernel<<<Nn / 64, 64, 0, stream>>>(wid, lrank, hist, sidx);
    wconv_kernel<<<786432 / 256, 256, 0, stream>>>(Wqkv, Wproj, W1, W2, wt);

    for (int l = 0; l < Ll; ++l) {
        const ushort* wqkvT  = wt + (size_t)l * 196608;
        const ushort* wprojT = wqkvT + 49152;
        const ushort* w1T    = wqkvT + 65536;
        const ushort* w2T    = wqkvT + 131072;
        const float* xsrc = (l == 0) ? x_in : x_ws;

        attn_fused_kernel<<<BN / 64, 256, 0, stream>>>(
            xsrc, x_ws, wqkvT, bqkv + l * 384, relb + l * Hh,
            wprojT, bproj + l * Cc, g1 + l * Cc, be1 + l * Cc, sidx);

        float* xdst = (l == Ll - 1) ? (float*)d_out : x_ws;
        mlp_fused_kernel<<<BN / 64, 256, 0, stream>>>(
            x_ws, xdst, w1T, b1 + l * 512, w2T, b2 + l * Cc,
            g2 + l * Cc, be2 + l * Cc);
    }
}

// Round 4
// 471.753 us; speedup vs baseline: 1.1476x; 1.1476x over previous
//
#include <hip/hip_runtime.h>
#include <hip/hip_bf16.h>
#include <math.h>

#define Nn 20480
#define Cc 128
#define Hh 8
#define Ll 4
#define NWw 320
#define BN 81920   // B*N

typedef short sv8 __attribute__((ext_vector_type(8)));
typedef __bf16 bfv8 __attribute__((ext_vector_type(8)));
typedef float f32x4 __attribute__((ext_vector_type(4)));

__device__ __forceinline__ f32x4 mfma16(sv8 a, sv8 b, f32x4 c) {
    return __builtin_amdgcn_mfma_f32_16x16x32_bf16(
        __builtin_bit_cast(bfv8, a), __builtin_bit_cast(bfv8, b), c, 0, 0, 0);
}
__device__ __forceinline__ ushort f2bf(float f) {
    uint u = __float_as_uint(f);
    u += 0x7fffu + ((u >> 16) & 1u);
    return (ushort)(u >> 16);
}
__device__ __forceinline__ float fast_gelu(float x) {
    float z = 0.7978845608f * (x + 0.044715f * x * x * x);
    return x * __builtin_amdgcn_rcpf(1.0f + __expf(-2.0f * z));
}

// ---------- stable counting sort of window_ids ----------
__global__ __launch_bounds__(64) void rank_kernel(const int* __restrict__ wid,
        int* __restrict__ lrank, int* __restrict__ hist) {
    __shared__ int keys[64];
    int c = blockIdx.x, lane = threadIdx.x;
    for (int j = lane; j < NWw; j += 64) hist[c * NWw + j] = 0;
    int i = c * 64 + lane;
    int w = wid[i];
    keys[lane] = w;
    __syncthreads();
    int rank = 0, total = 0;
    for (int j = 0; j < 64; ++j) {
        int kj = keys[j];
        total += (kj == w);
        rank += (j < lane && kj == w) ? 1 : 0;
    }
    lrank[i] = rank;
    if (rank == 0) hist[c * NWw + w] = total;
}
__global__ __launch_bounds__(64) void prefix_kernel(int* __restrict__ hist) {
    int w = blockIdx.x, lane = threadIdx.x;
    int running = 0;
    for (int it = 0; it < NWw / 64; ++it) {
        int c = it * 64 + lane;
        int v = hist[c * NWw + w];
        int orig = v;
        #pragma unroll
        for (int d = 1; d < 64; d <<= 1) {
            int tt = __shfl_up(v, d, 64);
            if (lane >= d) v += tt;
        }
        hist[c * NWw + w] = running + v - orig;
        running += __shfl(v, 63, 64);
    }
}
__global__ __launch_bounds__(64) void scatter_kernel(const int* __restrict__ wid,
        const int* __restrict__ lrank, const int* __restrict__ hist,
        int* __restrict__ sidx) {
    int c = blockIdx.x, lane = threadIdx.x;
    int i = c * 64 + lane;
    int w = wid[i];
    sidx[w * 64 + hist[c * NWw + w] + lrank[i]] = i;
}

// ---------- weight convert + transpose to bf16 [N][K] ----------
__global__ __launch_bounds__(256) void wconv_kernel(
    const float* __restrict__ Wqkv, const float* __restrict__ Wproj,
    const float* __restrict__ W1, const float* __restrict__ W2,
    ushort* __restrict__ wt) {
    int id = blockIdx.x * 256 + threadIdx.x;      // < 786432
    int l = id / 196608;
    int r = id % 196608;
    const float* src; int dst;
    if (r < 49152) { int n = r % 384, k = r / 384;
        src = Wqkv + l * 49152 + k * 384 + n; dst = l * 196608 + n * 128 + k; }
    else if (r < 65536) { int rr = r - 49152; int n = rr % 128, k = rr / 128;
        src = Wproj + l * 16384 + k * 128 + n; dst = l * 196608 + 49152 + n * 128 + k; }
    else if (r < 131072) { int rr = r - 65536; int n = rr % 512, k = rr / 512;
        src = W1 + l * 65536 + k * 512 + n; dst = l * 196608 + 65536 + n * 128 + k; }
    else { int rr = r - 131072; int n = rr % 128, k = rr / 128;
        src = W2 + l * 65536 + k * 128 + n; dst = l * 196608 + 131072 + n * 512 + k; }
    wt[dst] = f2bf(*src);
}

// ---------- fused attention block (unchanged from R3) ----------
__global__ __launch_bounds__(256, 2) void attn_fused_kernel(
    const float* __restrict__ xsrc, float* __restrict__ xdst,
    const ushort* __restrict__ wqkvT, const float* __restrict__ bqkv,
    const float* __restrict__ relb, const ushort* __restrict__ wprojT,
    const float* __restrict__ bproj, const float* __restrict__ g1,
    const float* __restrict__ be1, const int* __restrict__ sidx) {
    __shared__ __align__(16) ushort hl_[64][128];   // LN out; reused as attn-out
    __shared__ __align__(16) ushort qkn[64][256];   // q|k (swizzled)
    __shared__ __align__(16) ushort vT[128][76];    // V transposed [d][k]
    __shared__ __align__(16) ushort pt[4][16][76];  // P stage per wave
    __shared__ int ridx[64];

    int t = threadIdx.x;
    int wave = t >> 6, lane = t & 63;
    int lr = lane & 15, lg = lane >> 4;
    int wb = blockIdx.x;
    int bN = (wb / NWw) * Nn;
    int p0 = (wb % NWw) * 64;

    if (t < 64) ridx[t] = sidx[p0 + t];
    __syncthreads();

    // ---- phase 1: gather + LN1 -> hl_ (bf16, swizzled)
    {
        int hl2 = lane & 31, hb = lane >> 5;
        float4 gg = *(const float4*)(g1 + hl2 * 4);
        float4 bb = *(const float4*)(be1 + hl2 * 4);
        #pragma unroll
        for (int it = 0; it < 8; ++it) {
            int row = it * 8 + wave * 2 + hb;
            int gi = bN + ridx[row];
            float4 v = *(const float4*)(xsrc + (size_t)gi * Cc + hl2 * 4);
            float s = v.x + v.y + v.z + v.w;
            s += __shfl_xor(s, 1, 64);  s += __shfl_xor(s, 2, 64);
            s += __shfl_xor(s, 4, 64);  s += __shfl_xor(s, 8, 64);
            s += __shfl_xor(s, 16, 64);
            float mu = s * 0.0078125f;
            float d0 = v.x - mu, d1 = v.y - mu, d2 = v.z - mu, d3 = v.w - mu;
            float q = d0 * d0 + d1 * d1 + d2 * d2 + d3 * d3;
            q += __shfl_xor(q, 1, 64);  q += __shfl_xor(q, 2, 64);
            q += __shfl_xor(q, 4, 64);  q += __shfl_xor(q, 8, 64);
            q += __shfl_xor(q, 16, 64);
            float rs = rsqrtf(q * 0.0078125f + 1e-5f);
            uint2 pk;
            pk.x = (uint)f2bf(d0 * rs * gg.x + bb.x) | ((uint)f2bf(d1 * rs * gg.y + bb.y) << 16);
            pk.y = (uint)f2bf(d2 * rs * gg.z + bb.z) | ((uint)f2bf(d3 * rs * gg.w + bb.w) << 16);
            *(uint2*)&hl_[row][(hl2 * 4) ^ ((row & 7) << 3)] = pk;
        }
    }
    __syncthreads();

    // ---- phase 2: QKV GEMM; wave computes its own 2 heads' q,k,v (96 cols)
    {
        f32x4 acc[4][6] = {};
        #pragma unroll
        for (int ks = 0; ks < 4; ++ks) {
            int k0 = ks * 32 + lg * 8;
            sv8 a[4], b[6];
            #pragma unroll
            for (int rf = 0; rf < 4; ++rf) {
                int row = rf * 16 + lr;
                a[rf] = *(const sv8*)&hl_[row][k0 ^ ((row & 7) << 3)];
            }
            #pragma unroll
            for (int nf = 0; nf < 6; ++nf) {
                int gcol = (nf < 2 ? 32 * wave + nf * 16
                          : nf < 4 ? 128 + 32 * wave + (nf - 2) * 16
                                   : 256 + 32 * wave + (nf - 4) * 16) + lr;
                b[nf] = *(const sv8*)(wqkvT + (size_t)gcol * 128 + k0);
            }
            #pragma unroll
            for (int rf = 0; rf < 4; ++rf)
                #pragma unroll
                for (int nf = 0; nf < 6; ++nf)
                    acc[rf][nf] = mfma16(a[rf], b[nf], acc[rf][nf]);
        }
        #pragma unroll
        for (int nf = 0; nf < 6; ++nf) {
            int gcol = (nf < 2 ? 32 * wave + nf * 16
                      : nf < 4 ? 128 + 32 * wave + (nf - 2) * 16
                               : 256 + 32 * wave + (nf - 4) * 16) + lr;
            float bs = bqkv[gcol];
            if (nf < 4) {
                #pragma unroll
                for (int rf = 0; rf < 4; ++rf)
                    #pragma unroll
                    for (int r = 0; r < 4; ++r) {
                        int row = rf * 16 + lg * 4 + r;
                        qkn[row][gcol ^ ((row & 7) << 3)] = f2bf(acc[rf][nf][r] + bs);
                    }
            } else {
                int dcol = gcol - 256;
                #pragma unroll
                for (int rf = 0; rf < 4; ++rf) {
                    uint2 pk;
                    pk.x = (uint)f2bf(acc[rf][nf][0] + bs) | ((uint)f2bf(acc[rf][nf][1] + bs) << 16);
                    pk.y = (uint)f2bf(acc[rf][nf][2] + bs) | ((uint)f2bf(acc[rf][nf][3] + bs) << 16);
                    *(uint2*)&vT[dcol][rf * 16 + lg * 4] = pk;
                }
            }
        }
    }
    __syncthreads();   // qkn/vT ready; hl_ reads done -> safe to overwrite as attn-out

    // ---- phase 3: attention via swapped QK^T (S^T = K Q^T), 2 heads per wave
    f32x4 zz = {0.f, 0.f, 0.f, 0.f};
    #pragma unroll
    for (int hi = 0; hi < 2; ++hi) {
        int hh = wave * 2 + hi;
        float rb = relb[hh];
        sv8 bv[2];
        #pragma unroll
        for (int ks = 0; ks < 2; ++ks)
            bv[ks] = *(const sv8*)&vT[hh * 16 + lr][ks * 32 + lg * 8];
        sv8 aq[4], bk[4];
        sv8 z = {0, 0, 0, 0, 0, 0, 0, 0};
        bool lo = (lg < 2);
        #pragma unroll
        for (int f = 0; f < 4; ++f) {
            aq[f] = z; bk[f] = z;
            if (lo) {
                int row = f * 16 + lr;
                aq[f] = *(const sv8*)&qkn[row][(hh * 16 + lg * 8) ^ ((row & 7) << 3)];
                bk[f] = *(const sv8*)&qkn[row][(128 + hh * 16 + lg * 8) ^ ((row & 7) << 3)];
            }
        }
        f32x4 s[4][4];
        #pragma unroll
        for (int kt = 0; kt < 4; ++kt)
            #pragma unroll
            for (int qt = 0; qt < 4; ++qt)
                s[kt][qt] = mfma16(bk[kt], aq[qt], zz);

        f32x4 o[4];
        #pragma unroll
        for (int qt = 0; qt < 4; ++qt) {
            float v[16];
            #pragma unroll
            for (int kt = 0; kt < 4; ++kt)
                #pragma unroll
                for (int r = 0; r < 4; ++r)
                    v[kt * 4 + r] = s[kt][qt][r] * 0.25f + rb;
            float m0 = fmaxf(fmaxf(fmaxf(v[0], v[1]), fmaxf(v[2], v[3])),
                             fmaxf(fmaxf(v[4], v[5]), fmaxf(v[6], v[7])));
            float m1 = fmaxf(fmaxf(fmaxf(v[8], v[9]), fmaxf(v[10], v[11])),
                             fmaxf(fmaxf(v[12], v[13]), fmaxf(v[14], v[15])));
            float mx = fmaxf(m0, m1);
            mx = fmaxf(mx, __shfl_xor(mx, 16, 64));
            mx = fmaxf(mx, __shfl_xor(mx, 32, 64));
            float sum = 0.f;
            #pragma unroll
            for (int i = 0; i < 16; ++i) {
                v[i] = __expf(v[i] - mx);
                sum += v[i];
            }
            sum += __shfl_xor(sum, 16, 64);
            sum += __shfl_xor(sum, 32, 64);
            float inv = __builtin_amdgcn_rcpf(sum);
            #pragma unroll
            for (int kt = 0; kt < 4; ++kt) {
                uint2 pk;
                pk.x = (uint)f2bf(v[kt * 4 + 0] * inv) | ((uint)f2bf(v[kt * 4 + 1] * inv) << 16);
                pk.y = (uint)f2bf(v[kt * 4 + 2] * inv) | ((uint)f2bf(v[kt * 4 + 3] * inv) << 16);
                *(uint2*)&pt[wave][lr][kt * 16 + lg * 4] = pk;
            }
            sv8 ap0 = *(const sv8*)&pt[wave][lr][lg * 8];
            sv8 ap1 = *(const sv8*)&pt[wave][lr][32 + lg * 8];
            o[qt] = mfma16(ap0, bv[0], zz);
            o[qt] = mfma16(ap1, bv[1], o[qt]);
        }
        #pragma unroll
        for (int qt = 0; qt < 4; ++qt)
            #pragma unroll
            for (int r = 0; r < 4; ++r) {
                int row = qt * 16 + lg * 4 + r;
                hl_[row][(hh * 16 + lr) ^ ((row & 7) << 3)] = f2bf(o[qt][r]);
            }
    }
    __syncthreads();

    // ---- phase 4: proj + bias + residual, scatter to original rows
    {
        f32x4 acc[4][2] = {};
        #pragma unroll
        for (int ks = 0; ks < 4; ++ks) {
            int k0 = ks * 32 + lg * 8;
            sv8 a[4], b[2];
            #pragma unroll
            for (int rf = 0; rf < 4; ++rf) {
                int row = rf * 16 + lr;
                a[rf] = *(const sv8*)&hl_[row][k0 ^ ((row & 7) << 3)];
            }
            #pragma unroll
            for (int nf = 0; nf < 2; ++nf)
                b[nf] = *(const sv8*)(wprojT + (size_t)(wave * 32 + nf * 16 + lr) * 128 + k0);
            #pragma unroll
            for (int rf = 0; rf < 4; ++rf)
                #pragma unroll
                for (int nf = 0; nf < 2; ++nf)
                    acc[rf][nf] = mfma16(a[rf], b[nf], acc[rf][nf]);
        }
        #pragma unroll
        for (int nf = 0; nf < 2; ++nf) {
            int col = wave * 32 + nf * 16 + lr;
            float bs = bproj[col];
            #pragma unroll
            for (int rf = 0; rf < 4; ++rf)
                #pragma unroll
                for (int r = 0; r < 4; ++r) {
                    int row = rf * 16 + lg * 4 + r;
                    int gi = bN + ridx[row];
                    size_t ad = (size_t)gi * Cc + col;
                    xdst[ad] = xsrc[ad] + acc[rf][nf][r] + bs;
                }
        }
    }
}

// ---------- fused MLP block: LN2 -> MLP1+GELU -> MLP2 -> staged coalesced epilogue ----------
// R2 structure (no split-K, no spill): (256,2), hid[64][512], 2 main barriers.
__global__ __launch_bounds__(256, 2) void mlp_fused_kernel(
    const float* __restrict__ xsrc, float* __restrict__ xdst,
    const ushort* __restrict__ w1T, const float* __restrict__ b1,
    const ushort* __restrict__ w2T, const float* __restrict__ b2,
    const float* __restrict__ g2, const float* __restrict__ be2) {
    __shared__ __align__(16) ushort hl_[64][128];
    __shared__ __align__(16) ushort hid[64][512];   // reused as float[64][132] for epilogue
    int t = threadIdx.x, wave = t >> 6, lane = t & 63;
    int lr = lane & 15, lg = lane >> 4;
    int r0 = blockIdx.x * 64;

    // phase 1: LN2
    {
        int hl2 = lane & 31, hb = lane >> 5;
        float4 gg = *(const float4*)(g2 + hl2 * 4);
        float4 bb = *(const float4*)(be2 + hl2 * 4);
        #pragma unroll
        for (int it = 0; it < 8; ++it) {
            int row = it * 8 + wave * 2 + hb;
            float4 v = *(const float4*)(xsrc + (size_t)(r0 + row) * Cc + hl2 * 4);
            float s = v.x + v.y + v.z + v.w;
            s += __shfl_xor(s, 1, 64);  s += __shfl_xor(s, 2, 64);
            s += __shfl_xor(s, 4, 64);  s += __shfl_xor(s, 8, 64);
            s += __shfl_xor(s, 16, 64);
            float mu = s * 0.0078125f;
            float d0 = v.x - mu, d1 = v.y - mu, d2 = v.z - mu, d3 = v.w - mu;
            float q = d0 * d0 + d1 * d1 + d2 * d2 + d3 * d3;
            q += __shfl_xor(q, 1, 64);  q += __shfl_xor(q, 2, 64);
            q += __shfl_xor(q, 4, 64);  q += __shfl_xor(q, 8, 64);
            q += __shfl_xor(q, 16, 64);
            float rs = rsqrtf(q * 0.0078125f + 1e-5f);
            uint2 pk;
            pk.x = (uint)f2bf(d0 * rs * gg.x + bb.x) | ((uint)f2bf(d1 * rs * gg.y + bb.y) << 16);
            pk.y = (uint)f2bf(d2 * rs * gg.z + bb.z) | ((uint)f2bf(d3 * rs * gg.w + bb.w) << 16);
            *(uint2*)&hl_[row][(hl2 * 4) ^ ((row & 7) << 3)] = pk;
        }
    }
    __syncthreads();

    // phase 2: MLP1 + gelu -> hid (wave -> 128 cols)
    {
        f32x4 acc[4][8] = {};
        #pragma unroll
        for (int ks = 0; ks < 4; ++ks) {
            int k0 = ks * 32 + lg * 8;
            sv8 a[4], b[8];
            #pragma unroll
            for (int rf = 0; rf < 4; ++rf) {
                int row = rf * 16 + lr;
                a[rf] = *(const sv8*)&hl_[row][k0 ^ ((row & 7) << 3)];
            }
            #pragma unroll
            for (int nf = 0; nf < 8; ++nf)
                b[nf] = *(const sv8*)(w1T + (size_t)(wave * 128 + nf * 16 + lr) * 128 + k0);
            #pragma unroll
            for (int rf = 0; rf < 4; ++rf)
                #pragma unroll
                for (int nf = 0; nf < 8; ++nf)
                    acc[rf][nf] = mfma16(a[rf], b[nf], acc[rf][nf]);
        }
        #pragma unroll
        for (int nf = 0; nf < 8; ++nf) {
            int col = wave * 128 + nf * 16 + lr;
            float bs = b1[col];
            #pragma unroll
            for (int rf = 0; rf < 4; ++rf)
                #pragma unroll
                for (int r = 0; r < 4; ++r) {
                    int row = rf * 16 + lg * 4 + r;
                    hid[row][col ^ ((row & 7) << 3)] = f2bf(fast_gelu(acc[rf][nf][r] + bs));
                }
        }
    }
    __syncthreads();

    // phase 3: MLP2 (K=512) + staged coalesced epilogue
    {
        f32x4 acc2[4][2] = {};
        #pragma unroll
        for (int ks = 0; ks < 16; ++ks) {
            int k0 = ks * 32 + lg * 8;
            sv8 a[4], b[2];
            #pragma unroll
            for (int rf = 0; rf < 4; ++rf) {
                int row = rf * 16 + lr;
                a[rf] = *(const sv8*)&hid[row][k0 ^ ((row & 7) << 3)];
            }
            #pragma unroll
            for (int nf = 0; nf < 2; ++nf)
                b[nf] = *(const sv8*)(w2T + (size_t)(wave * 32 + nf * 16 + lr) * 512 + k0);
            #pragma unroll
            for (int rf = 0; rf < 4; ++rf)
                #pragma unroll
                for (int nf = 0; nf < 2; ++nf)
                    acc2[rf][nf] = mfma16(a[rf], b[nf], acc2[rf][nf]);
        }
        __syncthreads();                         // all hid reads done
        float* fh = (float*)hid;                 // [64][132] f32 stage (33.8 KB)
        #pragma unroll
        for (int nf = 0; nf < 2; ++nf) {
            int col = wave * 32 + nf * 16 + lr;
            float bs = b2[col];
            #pragma unroll
            for (int rf = 0; rf < 4; ++rf)
                #pragma unroll
                for (int r = 0; r < 4; ++r) {
                    int row = rf * 16 + lg * 4 + r;
                    fh[row * 132 + col] = acc2[rf][nf][r] + bs;
                }
        }
        __syncthreads();
        #pragma unroll
        for (int j = 0; j < 8; ++j) {
            int idx = t + j * 256;
            int row = idx >> 5, c4 = (idx & 31) * 4;
            size_t ad = (size_t)(r0 + row) * Cc + c4;
            float4 xv = *(const float4*)(xsrc + ad);
            float4 hv = *(const float4*)&fh[row * 132 + c4];
            float4 ov = {xv.x + hv.x, xv.y + hv.y, xv.z + hv.z, xv.w + hv.w};
            *(float4*)(xdst + ad) = ov;
        }
    }
}

extern "C" void kernel_launch(void* const* d_in, const int* in_sizes, int n_in,
                              void* d_out, int out_size, void* d_ws, size_t ws_size,
                              hipStream_t stream) {
    const float* x_in   = (const float*)d_in[0];
    const float* g1     = (const float*)d_in[1];
    const float* be1    = (const float*)d_in[2];
    const float* Wqkv   = (const float*)d_in[3];
    const float* bqkv   = (const float*)d_in[4];
    const float* relb   = (const float*)d_in[5];
    const float* Wproj  = (const float*)d_in[6];
    const float* bproj  = (const float*)d_in[7];
    const float* g2     = (const float*)d_in[8];
    const float* be2    = (const float*)d_in[9];
    const float* W1     = (const float*)d_in[10];
    const float* b1     = (const float*)d_in[11];
    const float* W2     = (const float*)d_in[12];
    const float* b2     = (const float*)d_in[13];
    const int*   wid    = (const int*)d_in[14];

    size_t off = 0;
    float* x_ws = (float*)d_ws;                      off += (size_t)BN * Cc * 4;
    ushort* wt  = (ushort*)((char*)d_ws + off);      off += (size_t)786432 * 2;
    int* sidx   = (int*)((char*)d_ws + off);         off += (size_t)Nn * 4;
    int* lrank  = (int*)((char*)d_ws + off);         off += (size_t)Nn * 4;
    int* hist   = (int*)((char*)d_ws + off);         off += (size_t)NWw * NWw * 4;
    if (ws_size < off) return;

    rank_kernel<<<Nn / 64, 64, 0, stream>>>(wid, lrank, hist);
    prefix_kernel<<<NWw, 64, 0, stream>>>(hist);
    scatter_kernel<<<Nn / 64, 64, 0, stream>>>(wid, lrank, hist, sidx);
    wconv_kernel<<<786432 / 256, 256, 0, stream>>>(Wqkv, Wproj, W1, W2, wt);

    for (int l = 0; l < Ll; ++l) {
        const ushort* wqkvT  = wt + (size_t)l * 196608;
        const ushort* wprojT = wqkvT + 49152;
        const ushort* w1T    = wqkvT + 65536;
        const ushort* w2T    = wqkvT + 131072;
        const float* xsrc = (l == 0) ? x_in : x_ws;

        attn_fused_kernel<<<BN / 64, 256, 0, stream>>>(
            xsrc, x_ws, wqkvT, bqkv + l * 384, relb + l * Hh,
            wprojT, bproj + l * Cc, g1 + l * Cc, be1 + l * Cc, sidx);

        float* xdst = (l == Ll - 1) ? (float*)d_out : x_ws;
        mlp_fused_kernel<<<BN / 64, 256, 0, stream>>>(
            x_ws, xdst, w1T, b1 + l * 512, w2T, b2 + l * Cc,
            g2 + l * Cc, be2 + l * Cc);
    }
}